// Round 21
// baseline (44.533 us; speedup 1.0000x reference)
//
#include <hip/hip_runtime.h>
#include <math.h>

// Problem constants: B=1, S=256, HID=1024, H=16, KV=8, D=64, N_REP=2
#define SCALE 0.125f   // 1/sqrt(64)
#define LOG2E 1.44269504088896340736f

typedef short short8 __attribute__((ext_vector_type(8)));
typedef float floatx4 __attribute__((ext_vector_type(4)));

static __device__ __forceinline__ ushort f2bf(float x) {
  uint32_t b = __float_as_uint(x);
  uint32_t r = (b + 0x7FFFu + ((b >> 16) & 1u)) >> 16;   // RNE
  return (ushort)r;
}
static __device__ __forceinline__ float bf2f(ushort u) {
  return __uint_as_float(((uint32_t)u) << 16);
}

// ---------------------------------------------------------------------------
// MFMA bf16 GEMM 1: X(256x1024) @ [Wq|Wk|Wv](1024x2048) -> QKV partials.
// K-split 4. grid = 512 (4 ksplit * 128 tiles), block = 256. (verified R8/R13)
// ---------------------------------------------------------------------------
__global__ __launch_bounds__(256) void gemm_qkv_kernel(
    const float* __restrict__ X, const float* __restrict__ Wq,
    const float* __restrict__ Wk, const float* __restrict__ Wv,
    float* __restrict__ Cp) {
  __shared__ ushort As[4096];
  __shared__ ushort Bs[4096];
  char* Asc = (char*)As;
  char* Bsc = (char*)Bs;
  const int bx = blockIdx.x;
  const int ks = bx >> 7;            // 0..3
  const int tile = bx & 127;         // 4 m-tiles x 32 n-tiles
  const int tile_n = tile & 31, tile_m = tile >> 5;
  const int n0 = tile_n * 64, m0 = tile_m * 64;
  const float* Bp; int ldb, bc0;
  if (n0 < 1024)      { Bp = Wq; ldb = 1024; bc0 = n0; }
  else if (n0 < 1536) { Bp = Wk; ldb = 512;  bc0 = n0 - 1024; }
  else                { Bp = Wv; ldb = 512;  bc0 = n0 - 1536; }
  const int t = threadIdx.x;
  const int arow = t >> 4, acg = t & 15;
  const int bng = t & 15;
  const int kbeg = ks * 256;
  float4 ra[4], rb0[2], rb1[2];
  auto LOAD = [&](int k0) {
    #pragma unroll
    for (int i = 0; i < 4; ++i)
      ra[i] = *reinterpret_cast<const float4*>(X + (size_t)(m0 + arow + 16 * i) * 1024 + k0 + acg * 4);
    #pragma unroll
    for (int i = 0; i < 2; ++i) {
      int k = 2 * ((t >> 4) + 16 * i);
      rb0[i] = *reinterpret_cast<const float4*>(Bp + (size_t)(k0 + k) * ldb + bc0 + bng * 4);
      rb1[i] = *reinterpret_cast<const float4*>(Bp + (size_t)(k0 + k + 1) * ldb + bc0 + bng * 4);
    }
  };
  LOAD(kbeg);
  const int wid = t >> 6, wr = wid >> 1, wc = wid & 1, lane = t & 63;
  const int lr = lane & 15, lk = lane >> 4;
  const int sw = (lr & 7) << 4;
  floatx4 acc[2][2];
  #pragma unroll
  for (int mt = 0; mt < 2; ++mt)
    #pragma unroll
    for (int nt = 0; nt < 2; ++nt)
      acc[mt][nt] = (floatx4){0.f, 0.f, 0.f, 0.f};
  for (int kt = 0; kt < 4; ++kt) {
    #pragma unroll
    for (int i = 0; i < 4; ++i) {
      int row = arow + 16 * i;
      ushort4 w;
      w.x = f2bf(ra[i].x); w.y = f2bf(ra[i].y); w.z = f2bf(ra[i].z); w.w = f2bf(ra[i].w);
      *reinterpret_cast<ushort4*>(Asc + row * 128 + ((acg * 8) ^ ((row & 7) << 4))) = w;
    }
    #pragma unroll
    for (int i = 0; i < 2; ++i) {
      int k = 2 * ((t >> 4) + 16 * i);
      const float* p0 = (const float*)&rb0[i];
      const float* p1 = (const float*)&rb1[i];
      #pragma unroll
      for (int j = 0; j < 4; ++j) {
        int n = bng * 4 + j;
        uint32_t v = (uint32_t)f2bf(p0[j]) | ((uint32_t)f2bf(p1[j]) << 16);
        *reinterpret_cast<uint32_t*>(Bsc + n * 128 + ((k * 2) ^ ((n & 7) << 4))) = v;
      }
    }
    __syncthreads();
    if (kt + 1 < 4) LOAD(kbeg + 64 * (kt + 1));
    #pragma unroll
    for (int kc = 0; kc < 2; ++kc) {
      short8 af[2], bf[2];
      #pragma unroll
      for (int mt = 0; mt < 2; ++mt)
        af[mt] = *reinterpret_cast<const short8*>(
            Asc + (wr * 32 + mt * 16 + lr) * 128 + ((kc * 64 + lk * 16) ^ sw));
      #pragma unroll
      for (int nt = 0; nt < 2; ++nt)
        bf[nt] = *reinterpret_cast<const short8*>(
            Bsc + (wc * 32 + nt * 16 + lr) * 128 + ((kc * 64 + lk * 16) ^ sw));
      #pragma unroll
      for (int mt = 0; mt < 2; ++mt)
        #pragma unroll
        for (int nt = 0; nt < 2; ++nt)
          acc[mt][nt] = __builtin_amdgcn_mfma_f32_16x16x32_bf16(af[mt], bf[nt], acc[mt][nt], 0, 0, 0);
    }
    __syncthreads();
  }
  float* Co = Cp + (size_t)ks * 524288;
  #pragma unroll
  for (int mt = 0; mt < 2; ++mt)
    #pragma unroll
    for (int nt = 0; nt < 2; ++nt)
      #pragma unroll
      for (int r = 0; r < 4; ++r) {
        int row = wr * 32 + mt * 16 + lk * 4 + r;
        int col = wc * 32 + nt * 16 + lr;
        Co[(size_t)(m0 + row) * 2048 + n0 + col] = acc[mt][nt][r];
      }
}

// ---------------------------------------------------------------------------
// Reduce the 4 QKV partials + RoPE on q/k heads. grid = 1280, block = 256.
// ---------------------------------------------------------------------------
__global__ __launch_bounds__(256) void rope_reduce_kernel(
    const float* __restrict__ Cp, float* __restrict__ QKV,
    const float* __restrict__ cs, const float* __restrict__ sn) {
  int idx = blockIdx.x * 256 + threadIdx.x;
  const float* P0 = Cp;
  const float* P1 = Cp + 524288;
  const float* P2p = Cp + 1048576;
  const float* P3 = Cp + 1572864;
  if (idx < 196608) {                 // 256 s * 24 heads * 32 pairs
    int dp = idx & 31;
    int head = (idx >> 5) % 24;       // 0..15 q heads, 16..23 k heads
    int s = idx / 768;
    int base = s * 2048 + head * 64;
    int a1 = base + dp, a2 = base + dp + 32;
    float x1 = P0[a1] + P1[a1] + P2p[a1] + P3[a1];
    float x2 = P0[a2] + P1[a2] + P2p[a2] + P3[a2];
    float c1 = cs[s * 64 + dp],      s1v = sn[s * 64 + dp];
    float c2 = cs[s * 64 + dp + 32], s2v = sn[s * 64 + dp + 32];
    QKV[a1] = x1 * c1 - x2 * s1v;   // q' = q*cos + rot_half(q)*sin
    QKV[a2] = x2 * c2 + x1 * s2v;
  } else {
    int i2 = idx - 196608;            // 131072 v elements
    int s = i2 >> 9, c = 1536 + (i2 & 511);
    int a = s * 2048 + c;
    QKV[a] = P0[a] + P1[a] + P2p[a] + P3[a];
  }
}

// ---------------------------------------------------------------------------
// FUSED QK^T + softmax + p_diff + PV, v4: TWO-ROW INTERLEAVED t-loop.
// Wave's rows A (s=jj<=127) and B (s=255-jj) share kv words over A's range:
// seg1 [0,end1) processes BOTH rows per kv read (2x ILP, kv reads halved);
// seg2 [end1,end2) row B only. Causal mask baked into awsh (-1000 -> e=ep=0)
// makes seg1's overshoot past sA exactly zero. Native v_exp, hoisted ep,
// stride-258 kvT (all verified R20).
// grid = 256 (8 g * 32 u), block = 512.
// ---------------------------------------------------------------------------
__global__ __launch_bounds__(512) void pdiff_fused_kernel(
    const float* __restrict__ QKV, float* __restrict__ pOut,
    float* __restrict__ qkpart, float* __restrict__ vpart,
    float* __restrict__ attn_out) {
  __shared__ ushort ksh[16384];       // 32KB swizzled [t][d] bf16 (MFMA B)
  __shared__ uint32_t kvT[64 * 258];  // 64.5KB transposed [d][t]: k lo | v hi
  __shared__ ushort qsh[1024];        // 2KB  swizzled [a][d] bf16 (16 rows)
  __shared__ ushort awsh[16][264];    // 8.25KB bf16 (scale^2*log2e*qk, masked)
  __shared__ float  epsh[16][260];    // 16.25KB fp32 2^(8*aw) per row
  char* kshc = (char*)ksh;
  char* qshc = (char*)qsh;
  const int g = blockIdx.x >> 5;
  const int u = blockIdx.x & 31;
  const int t = threadIdx.x;
  // stage k (swizzled, for MFMA) + kvT (transposed packed, for t-loop)
  #pragma unroll
  for (int i = 0; i < 8; ++i) {
    int fi = t + i * 512;              // 4096 float4 slots
    int tt = fi >> 4, c = (fi & 15) * 4;
    float4 kv = *reinterpret_cast<const float4*>(QKV + (size_t)tt * 2048 + 1024 + g * 64 + c);
    float4 vv = *reinterpret_cast<const float4*>(QKV + (size_t)tt * 2048 + 1536 + g * 64 + c);
    ushort4 wk;
    wk.x = f2bf(kv.x); wk.y = f2bf(kv.y); wk.z = f2bf(kv.z); wk.w = f2bf(kv.w);
    *reinterpret_cast<ushort4*>(kshc + tt * 128 + ((c * 2) ^ ((tt & 7) << 4))) = wk;
    kvT[(c + 0) * 258 + tt] = (uint32_t)wk.x | ((uint32_t)f2bf(vv.x) << 16);
    kvT[(c + 1) * 258 + tt] = (uint32_t)wk.y | ((uint32_t)f2bf(vv.y) << 16);
    kvT[(c + 2) * 258 + tt] = (uint32_t)wk.z | ((uint32_t)f2bf(vv.z) << 16);
    kvT[(c + 3) * 258 + tt] = (uint32_t)wk.w | ((uint32_t)f2bf(vv.w) << 16);
  }
  { // stage the 16 q rows: a = pr*8 + mr*4 + jo
    int a = t >> 5;                    // 0..15
    int c = (t & 31) * 2;              // 0..62
    int pr = a >> 3, mr = (a >> 2) & 1, jo = a & 3;
    int s = mr ? 255 - (4 * u + jo) : 4 * u + jo;
    int hh = 2 * g + pr;
    float2 qv = *reinterpret_cast<const float2*>(QKV + (size_t)s * 2048 + hh * 64 + c);
    uint32_t pk = (uint32_t)f2bf(qv.x) | ((uint32_t)f2bf(qv.y) << 16);
    *reinterpret_cast<uint32_t*>(qshc + a * 128 + ((c * 2) ^ ((a & 7) << 4))) = pk;
  }
  __syncthreads();
  const int w = t >> 6, lane = t & 63;
  const int lr = lane & 15, lk = lane >> 4;
  const int sw = (lr & 7) << 4;
  const float AWS = SCALE * SCALE * LOG2E;
  // QK^T: 16 col-tiles, 2 per wave; write awsh with causal mask baked in
  #pragma unroll
  for (int q2 = 0; q2 < 2; ++q2) {
    int nt = 2 * w + q2;
    floatx4 acc = (floatx4){0.f, 0.f, 0.f, 0.f};
    #pragma unroll
    for (int kc = 0; kc < 2; ++kc) {
      short8 af = *reinterpret_cast<const short8*>(
          qshc + lr * 128 + ((kc * 64 + lk * 16) ^ sw));
      int tt = nt * 16 + lr;
      short8 bf = *reinterpret_cast<const short8*>(
          kshc + tt * 128 + ((kc * 64 + lk * 16) ^ ((tt & 7) << 4)));
      acc = __builtin_amdgcn_mfma_f32_16x16x32_bf16(af, bf, acc, 0, 0, 0);
    }
    #pragma unroll
    for (int r = 0; r < 4; ++r) {
      int a = lk * 4 + r;
      int pr = a >> 3, mr = (a >> 2) & 1, jo = a & 3;
      int sa = mr ? 255 - (4 * u + jo) : 4 * u + jo;
      int tc = nt * 16 + lr;
      awsh[a][tc] = f2bf((tc <= sa) ? acc[r] * AWS : -1000.0f);
    }
  }
  __syncthreads();
  const int pr = w & 1, jo = w >> 1;
  const int h = 2 * g + pr;
  const int jj = 4 * u + jo;
  const int aA = pr * 8 + jo;          // row A: s = jj
  const int aB = pr * 8 + 4 + jo;      // row B: s = 255-jj
  const int sA = jj, sB = 255 - jj;
  // precompute ep = 2^(8*aw) fp32 for this wave's OWN two rows (no barrier:
  // each wave reads back only rows it wrote; wave-internal lgkmcnt orders it)
  #pragma unroll
  for (int i = 0; i < 4; ++i) {
    int tc = lane + i * 64;
    epsh[aA][tc] = __builtin_amdgcn_exp2f(8.0f * bf2f(awsh[aA][tc]));
    epsh[aB][tc] = __builtin_amdgcn_exp2f(8.0f * bf2f(awsh[aB][tc]));
  }
  // interleaved t-loop: seg1 both rows (shared kv), seg2 row B tail
  float cdA = (SCALE * LOG2E) * QKV[(size_t)sA * 2048 + h * 64 + lane];
  float cdB = (SCALE * LOG2E) * QKV[(size_t)sB * 2048 + h * 64 + lane];
  float S1A = 0.f, S2A = 0.f, S3A = 0.f, SpA = 0.f, P2A = 0.f, AVA = 0.f;
  float S1B = 0.f, S2B = 0.f, S3B = 0.f, SpB = 0.f, P2B = 0.f, AVB = 0.f;
  const uint32_t* kvrow = &kvT[lane * 258];
  const ushort* awA = awsh[aA];
  const ushort* awB = awsh[aB];
  const float* epA = epsh[aA];
  const float* epB = epsh[aB];
  const int end1 = (sA + 4) & ~3;
  const int end2 = (sB + 4) & ~3;
  #pragma unroll 2
  for (int tb = 0; tb < end1; tb += 4) {
    uint2 kv0 = *reinterpret_cast<const uint2*>(&kvrow[tb]);
    uint2 kv1 = *reinterpret_cast<const uint2*>(&kvrow[tb + 2]);
    float4 eA4 = *reinterpret_cast<const float4*>(&epA[tb]);
    float4 eB4 = *reinterpret_cast<const float4*>(&epB[tb]);
    ushort4 aA4 = *reinterpret_cast<const ushort4*>(&awA[tb]);
    ushort4 aB4 = *reinterpret_cast<const ushort4*>(&awB[tb]);
    uint32_t kvj[4] = {kv0.x, kv0.y, kv1.x, kv1.y};
    ushort aAj[4] = {aA4.x, aA4.y, aA4.z, aA4.w};
    ushort aBj[4] = {aB4.x, aB4.y, aB4.z, aB4.w};
    float eAj[4] = {eA4.x, eA4.y, eA4.z, eA4.w};
    float eBj[4] = {eB4.x, eB4.y, eB4.z, eB4.w};
    #pragma unroll
    for (int j = 0; j < 4; ++j) {
      float kf = __uint_as_float(kvj[j] << 16);
      float vf = __uint_as_float(kvj[j] & 0xFFFF0000u);
      float eA = __builtin_amdgcn_exp2f(fmaf(-cdA, kf, bf2f(aAj[j])));
      float eB = __builtin_amdgcn_exp2f(fmaf(-cdB, kf, bf2f(aBj[j])));
      float pA = eAj[j], pB = eBj[j];
      S1A += eA;             S1B += eB;
      S2A = fmaf(eA, eA, S2A); S2B = fmaf(eB, eB, S2B);
      S3A = fmaf(eA, pA, S3A); S3B = fmaf(eB, pB, S3B);
      SpA += pA;             SpB += pB;
      P2A = fmaf(pA, pA, P2A); P2B = fmaf(pB, pB, P2B);
      AVA = fmaf(pA, vf, AVA); AVB = fmaf(pB, vf, AVB);
    }
  }
  #pragma unroll 2
  for (int tb = end1; tb < end2; tb += 4) {
    uint2 kv0 = *reinterpret_cast<const uint2*>(&kvrow[tb]);
    uint2 kv1 = *reinterpret_cast<const uint2*>(&kvrow[tb + 2]);
    float4 eB4 = *reinterpret_cast<const float4*>(&epB[tb]);
    ushort4 aB4 = *reinterpret_cast<const ushort4*>(&awB[tb]);
    uint32_t kvj[4] = {kv0.x, kv0.y, kv1.x, kv1.y};
    ushort aBj[4] = {aB4.x, aB4.y, aB4.z, aB4.w};
    float eBj[4] = {eB4.x, eB4.y, eB4.z, eB4.w};
    #pragma unroll
    for (int j = 0; j < 4; ++j) {
      float kf = __uint_as_float(kvj[j] << 16);
      float vf = __uint_as_float(kvj[j] & 0xFFFF0000u);
      float eB = __builtin_amdgcn_exp2f(fmaf(-cdB, kf, bf2f(aBj[j])));
      float pB = eBj[j];
      S1B += eB;
      S2B = fmaf(eB, eB, S2B);
      S3B = fmaf(eB, pB, S3B);
      SpB += pB;
      P2B = fmaf(pB, pB, P2B);
      AVB = fmaf(pB, vf, AVB);
    }
  }
  // finalize both rows
  {
    float invS1 = 1.f / S1A, invSp = 1.f / SpA;
    float qkA = S2A * invS1 * invS1 - 2.f * S3A * invS1 * invSp + P2A * invSp * invSp;
    float avA = AVA * invSp;
    attn_out[(size_t)sA * 1024 + h * 64 + lane] = avA;
    size_t rowbase = ((size_t)h * 256 + sA) * 256;
    #pragma unroll
    for (int i = 0; i < 4; ++i) {
      int tc = lane + i * 64;
      pOut[rowbase + tc] = epA[tc] * invSp;
    }
    float invS1B = 1.f / S1B, invSpB = 1.f / SpB;
    float qkB = S2B * invS1B * invS1B - 2.f * S3B * invS1B * invSpB + P2B * invSpB * invSpB;
    float avB = AVB * invSpB;
    attn_out[(size_t)sB * 1024 + h * 64 + lane] = avB;
    size_t rowbaseB = ((size_t)h * 256 + sB) * 256;
    #pragma unroll
    for (int i = 0; i < 4; ++i) {
      int tc = lane + i * 64;
      pOut[rowbaseB + tc] = epB[tc] * invSpB;
    }
    qkpart[((size_t)h * 128 + jj) * 64 + lane] = qkA + qkB;
    vpart [((size_t)h * 128 + jj) * 64 + lane] = fabsf(avA) + fabsf(avB);
  }
}

// ---------------------------------------------------------------------------
// GEMM 2 + tail in ONE dispatch. Blocks 0..255: 32x32-tile FULL-K bf16 MFMA,
// direct write to out. Blocks 256..263: qk/v/o importance reductions.
// grid = 264, block = 256.  (verified R15)
// ---------------------------------------------------------------------------
__global__ __launch_bounds__(256) void gemm_o_tail_kernel(
    const float* __restrict__ A, const float* __restrict__ W,
    const float* __restrict__ qkpart, const float* __restrict__ vpart,
    float* __restrict__ out, float* __restrict__ qkout,
    float* __restrict__ vout, float* __restrict__ oout) {
  __shared__ ushort As[2048];   // 32 rows x 64 k bf16, XOR swizzle
  __shared__ ushort Bs[2048];   // 32 n    x 64 k
  char* Asc = (char*)As;
  char* Bsc = (char*)Bs;
  const int b = blockIdx.x, t = threadIdx.x;
  if (b < 256) {
    const int tm = b >> 5, tn = b & 31;       // 8 m x 32 n tiles
    const int m0 = tm * 32, n0 = tn * 32;
    const int arow = t >> 3, aslot = t & 7;   // A: 32 rows x 16 slots
    const int kp = t >> 3, ng = t & 7;        // B: 32 kpairs x 8 ngroups
    float4 ra[2], rb0, rb1;
    auto LOAD = [&](int k0) {
      #pragma unroll
      for (int i = 0; i < 2; ++i)
        ra[i] = *reinterpret_cast<const float4*>(A + (size_t)(m0 + arow) * 1024 + k0 + (aslot + 8 * i) * 4);
      rb0 = *reinterpret_cast<const float4*>(W + (size_t)(k0 + 2 * kp) * 1024 + n0 + ng * 4);
      rb1 = *reinterpret_cast<const float4*>(W + (size_t)(k0 + 2 * kp + 1) * 1024 + n0 + ng * 4);
    };
    LOAD(0);
    const int wid = t >> 6, qm = wid >> 1, qn = wid & 1, lane = t & 63;
    const int lr = lane & 15, lk = lane >> 4;
    const int sw = (lr & 7) << 4;
    floatx4 acc = (floatx4){0.f, 0.f, 0.f, 0.f};
    for (int kt = 0; kt < 16; ++kt) {
      #pragma unroll
      for (int i = 0; i < 2; ++i) {
        int c = (aslot + 8 * i) * 4;
        ushort4 wv;
        wv.x = f2bf(ra[i].x); wv.y = f2bf(ra[i].y); wv.z = f2bf(ra[i].z); wv.w = f2bf(ra[i].w);
        *reinterpret_cast<ushort4*>(Asc + arow * 128 + ((c * 2) ^ ((arow & 7) << 4))) = wv;
      }
      {
        const float* p0 = (const float*)&rb0;
        const float* p1 = (const float*)&rb1;
        #pragma unroll
        for (int j = 0; j < 4; ++j) {
          int n = ng * 4 + j;
          uint32_t v = (uint32_t)f2bf(p0[j]) | ((uint32_t)f2bf(p1[j]) << 16);
          *reinterpret_cast<uint32_t*>(Bsc + n * 128 + ((kp * 4) ^ ((n & 7) << 4))) = v;
        }
      }
      __syncthreads();
      if (kt + 1 < 16) LOAD(64 * (kt + 1));
      #pragma unroll
      for (int kc = 0; kc < 2; ++kc) {
        short8 af = *reinterpret_cast<const short8*>(
            Asc + (qm * 16 + lr) * 128 + ((kc * 64 + lk * 16) ^ sw));
        short8 bf = *reinterpret_cast<const short8*>(
            Bsc + (qn * 16 + lr) * 128 + ((kc * 64 + lk * 16) ^ sw));
        acc = __builtin_amdgcn_mfma_f32_16x16x32_bf16(af, bf, acc, 0, 0, 0);
      }
      __syncthreads();
    }
    #pragma unroll
    for (int r = 0; r < 4; ++r) {
      int row = m0 + qm * 16 + lk * 4 + r;
      int col = n0 + qn * 16 + lr;
      out[(size_t)row * 1024 + col] = acc[r];
    }
  } else {
    int idx = (b - 256) * 256 + t;            // 0..2047
    if (idx < 1024) {
      int h = idx >> 6, d = idx & 63;
      float sum = 0.f;
      for (int j = 0; j < 128; ++j) sum += qkpart[((size_t)h * 128 + j) * 64 + d];
      qkout[idx] = sum;
    } else {
      int c = idx - 1024;
      int h = c >> 6, d = c & 63;
      float sum = 0.f;
      for (int j = 0; j < 128; ++j) sum += vpart[((size_t)h * 128 + j) * 64 + d];
      vout[c] = sum;
      oout[c] = sum;
    }
  }
}

// ---------------------------------------------------------------------------
extern "C" void kernel_launch(void* const* d_in, const int* in_sizes, int n_in,
                              void* d_out, int out_size, void* d_ws, size_t ws_size,
                              hipStream_t stream) {
  const float* X    = (const float*)d_in[0];   // hidden_states (1,256,1024)
  const float* cosp = (const float*)d_in[1];   // (1,256,64)
  const float* sinp = (const float*)d_in[2];   // (1,256,64)
  // d_in[3] attention_mask: causal, implemented analytically
  const float* Wq   = (const float*)d_in[4];   // (1024,1024)
  const float* Wk   = (const float*)d_in[5];   // (1024,512)
  const float* Wv   = (const float*)d_in[6];   // (1024,512)
  const float* Wo   = (const float*)d_in[7];   // (1024,1024)

  float* out  = (float*)d_out;                 // 262144
  float* pOut = out + 262144;                  // 1048576
  float* qki  = pOut + 1048576;                // 1024
  float* vi   = qki + 1024;                    // 1024
  float* oi   = vi + 1024;                     // 1024

  float* ws       = (float*)d_ws;
  float* QKV      = ws;                        // 524288 (s-major, 2048 cols: q|k|v)
  float* attn_out = ws + 524288;               // 262144
  float* qkpart   = ws + 786432;               // 131072
  float* vpart    = ws + 917504;               // 131072
  float* scratch  = ws + 1048576;              // 2097152 (QKV partials x4)

  hipLaunchKernelGGL(gemm_qkv_kernel, dim3(512), dim3(256), 0, stream, X, Wq, Wk, Wv, scratch);
  hipLaunchKernelGGL(rope_reduce_kernel, dim3(1280), dim3(256), 0, stream, scratch, QKV, cosp, sinp);
  hipLaunchKernelGGL(pdiff_fused_kernel, dim3(256), dim3(512), 0, stream, QKV, pOut, qkpart, vpart, attn_out);
  hipLaunchKernelGGL(gemm_o_tail_kernel, dim3(264), dim3(256), 0, stream, attn_out, Wo, qkpart, vpart, out, qki, vi, oi);
}